// Round 6
// baseline (1797.393 us; speedup 1.0000x reference)
//
#include <hip/hip_runtime.h>
#include <hip/hip_bf16.h>

typedef __attribute__((ext_vector_type(4))) float f32x4;
typedef __attribute__((ext_vector_type(8))) short short8;
typedef __attribute__((ext_vector_type(4))) int i32x4;
typedef __attribute__((ext_vector_type(2))) unsigned int u32x2;
typedef __attribute__((ext_vector_type(4))) unsigned short u16x4;

static __device__ __forceinline__ unsigned short f2bf(float f) {
  unsigned u = __builtin_bit_cast(unsigned, f);
  u = u + 0x7FFFu + ((u >> 16) & 1u);   // RNE
  return (unsigned short)(u >> 16);
}
static __device__ __forceinline__ float bf2f(unsigned short b) {
  unsigned u = ((unsigned)b) << 16;
  return __builtin_bit_cast(float, u);
}
static __device__ __forceinline__ float sigmoidf_fast(float x) {
  return __builtin_amdgcn_rcpf(1.f + __expf(-x));
}
static __device__ __forceinline__ float tanhf_fast(float x) {
  x = fminf(20.f, fmaxf(-20.f, x));
  float e = __expf(2.f * x);
  return (e - 1.f) * __builtin_amdgcn_rcpf(e + 1.f);
}

// ---------------- cast f32 -> hi/lo bf16 pair (RNE hi) ----------------
__global__ void cast_split_kernel(const float* __restrict__ in,
                                  unsigned short* __restrict__ oh,
                                  unsigned short* __restrict__ ol, int n4) {
  int i = blockIdx.x * blockDim.x + threadIdx.x;
  if (i >= n4) return;
  f32x4 v = ((const f32x4*)in)[i];
  u16x4 h, l;
#pragma unroll
  for (int j = 0; j < 4; ++j) {
    unsigned short hb = f2bf(v[j]);
    h[j] = hb;
    l[j] = f2bf(v[j] - bf2f(hb));
  }
  ((u16x4*)oh)[i] = h;
  ((u16x4*)ol)[i] = l;
}

// ---------------- transpose + cast: (R,C) f32 -> (C,R) bf16 ----------------
__global__ void tcast_kernel(const float* __restrict__ in,
                             unsigned short* __restrict__ out, int R, int C) {
  int i = blockIdx.x * blockDim.x + threadIdx.x;
  if (i >= R * C) return;
  int r = i / C, c = i % C;
  out[(size_t)c * R + r] = f2bf(in[i]);
}

// ---------------- transpose + split cast: (R,C) f32 -> (C,R) hi/lo bf16 ----------------
__global__ void tcast_split_kernel(const float* __restrict__ in,
                                   unsigned short* __restrict__ oh,
                                   unsigned short* __restrict__ ol, int R, int C) {
  int i = blockIdx.x * blockDim.x + threadIdx.x;
  if (i >= R * C) return;
  int r = i / C, c = i % C;
  float v = in[i];
  unsigned short hb = f2bf(v);
  oh[(size_t)c * R + r] = hb;
  ol[(size_t)c * R + r] = f2bf(v - bf2f(hb));
}

// ---------------- f gate: one wave per token row (pure f32) ----------------
__global__ __launch_bounds__(256) void fgate_kernel(const float* __restrict__ x,
                                                    const float* __restrict__ Wf,
                                                    const float* __restrict__ bfv,
                                                    float* __restrict__ fbuf) {
  int wid = (blockIdx.x * blockDim.x + threadIdx.x) >> 6;  // token row 0..4095
  int lane = threadIdx.x & 63;
  const float* xr = x + (size_t)wid * 1024;
  float acc[8] = {0.f, 0.f, 0.f, 0.f, 0.f, 0.f, 0.f, 0.f};
#pragma unroll 4
  for (int it = 0; it < 16; ++it) {
    int d = it * 64 + lane;
    float xv = xr[d];
    f32x4 w0 = *(const f32x4*)(Wf + (size_t)d * 8);
    f32x4 w1 = *(const f32x4*)(Wf + (size_t)d * 8 + 4);
    acc[0] += xv * w0[0]; acc[1] += xv * w0[1];
    acc[2] += xv * w0[2]; acc[3] += xv * w0[3];
    acc[4] += xv * w1[0]; acc[5] += xv * w1[1];
    acc[6] += xv * w1[2]; acc[7] += xv * w1[3];
  }
#pragma unroll
  for (int n = 0; n < 8; ++n) {
#pragma unroll
    for (int m = 1; m < 64; m <<= 1) acc[n] += __shfl_xor(acc[n], m, 64);
  }
  if (lane == 0) {
#pragma unroll
    for (int n = 0; n < 8; ++n)
      fbuf[(size_t)wid * 8 + n] = sigmoidf_fast(acc[n] + bfv[n]);
  }
}

// ---------------- causal depthwise conv (KC=4) + SiLU, all 3 tensors ----------------
__global__ void conv_silu_kernel(const float* __restrict__ pre,
                                 const float* __restrict__ cwq,
                                 const float* __restrict__ cwk,
                                 const float* __restrict__ cwv,
                                 float* __restrict__ outb) {
  int i = blockIdx.x * blockDim.x + threadIdx.x;  // B*L*512
  int which = blockIdx.y;
  const float* cw = (which == 0) ? cwq : (which == 1) ? cwk : cwv;
  const float* p = pre + (size_t)which * 2097152 + i;
  int c = i & 511;
  int l = (i >> 9) & 1023;
  float w0 = cw[c * 4 + 0], w1 = cw[c * 4 + 1], w2 = cw[c * 4 + 2], w3 = cw[c * 4 + 3];
  float acc = w3 * p[0];
  if (l >= 1) acc += w2 * p[-512];
  if (l >= 2) acc += w1 * p[-1024];
  if (l >= 3) acc += w0 * p[-1536];
  outb[(size_t)which * 2097152 + i] = acc * sigmoidf_fast(acc);
}

// ---------------- plain bf16 MFMA GEMM: C(M,Nd) = A * Bt^T ----------------
__global__ __launch_bounds__(256) void gemm_bf16_kernel(
    const unsigned short* __restrict__ A, const unsigned short* __restrict__ Bt,
    float* __restrict__ C, int Kd, int Nd, size_t BtStride, size_t CStride) {
  __shared__ unsigned short Ash[128][40];
  __shared__ unsigned short Bsh[128][40];
  const int tid = threadIdx.x;
  const int wave = tid >> 6, lane = tid & 63;
  const int g = lane >> 4, lr = lane & 15;
  const int m0 = blockIdx.x * 128, n0 = blockIdx.y * 128;
  const unsigned short* Bz = Bt + blockIdx.z * BtStride;
  float* Cz = C + blockIdx.z * CStride;
  const int wm = (wave >> 1) * 64, wn = (wave & 1) * 64;

  f32x4 acc[4][4];
#pragma unroll
  for (int a = 0; a < 4; ++a)
#pragma unroll
    for (int bq = 0; bq < 4; ++bq) acc[a][bq] = (f32x4){0.f, 0.f, 0.f, 0.f};

  for (int k0 = 0; k0 < Kd; k0 += 32) {
#pragma unroll
    for (int it = 0; it < 2; ++it) {
      int cch = tid + 256 * it;
      int r = cch >> 2, cc = cch & 3;
      *(i32x4*)&Ash[r][cc * 8] = *(const i32x4*)(A + (size_t)(m0 + r) * Kd + k0 + cc * 8);
      *(i32x4*)&Bsh[r][cc * 8] = *(const i32x4*)(Bz + (size_t)(n0 + r) * Kd + k0 + cc * 8);
    }
    __syncthreads();
    short8 af[4], bfr[4];
#pragma unroll
    for (int mt = 0; mt < 4; ++mt) af[mt] = *(const short8*)&Ash[wm + mt * 16 + lr][g * 8];
#pragma unroll
    for (int nt = 0; nt < 4; ++nt) bfr[nt] = *(const short8*)&Bsh[wn + nt * 16 + lr][g * 8];
#pragma unroll
    for (int mt = 0; mt < 4; ++mt)
#pragma unroll
      for (int nt = 0; nt < 4; ++nt)
        acc[mt][nt] = __builtin_amdgcn_mfma_f32_16x16x32_bf16(af[mt], bfr[nt], acc[mt][nt], 0, 0, 0);
    __syncthreads();
  }
#pragma unroll
  for (int mt = 0; mt < 4; ++mt)
#pragma unroll
    for (int nt = 0; nt < 4; ++nt)
#pragma unroll
      for (int r = 0; r < 4; ++r) {
        int m = m0 + wm + mt * 16 + g * 4 + r;
        int n = n0 + wn + nt * 16 + lr;
        Cz[(size_t)m * Nd + n] = acc[mt][nt][r];
      }
}

// ---------------- split-bf16 (3-term f32-emulation) GEMM ----------------
__global__ __launch_bounds__(256) void gemm_split_kernel(
    const unsigned short* __restrict__ Ah, const unsigned short* __restrict__ Al,
    const unsigned short* __restrict__ Bth, const unsigned short* __restrict__ Btl,
    float* __restrict__ C, int Kd, int Nd, size_t BtStride, size_t CStride) {
  __shared__ unsigned short AshH[128][40];
  __shared__ unsigned short AshL[128][40];
  __shared__ unsigned short BshH[128][40];
  __shared__ unsigned short BshL[128][40];
  const int tid = threadIdx.x;
  const int wave = tid >> 6, lane = tid & 63;
  const int g = lane >> 4, lr = lane & 15;
  const int m0 = blockIdx.x * 128, n0 = blockIdx.y * 128;
  const unsigned short* Bzh = Bth + blockIdx.z * BtStride;
  const unsigned short* Bzl = Btl + blockIdx.z * BtStride;
  float* Cz = C + blockIdx.z * CStride;
  const int wm = (wave >> 1) * 64, wn = (wave & 1) * 64;

  f32x4 acc[4][4];
#pragma unroll
  for (int a = 0; a < 4; ++a)
#pragma unroll
    for (int bq = 0; bq < 4; ++bq) acc[a][bq] = (f32x4){0.f, 0.f, 0.f, 0.f};

  for (int k0 = 0; k0 < Kd; k0 += 32) {
#pragma unroll
    for (int it = 0; it < 2; ++it) {
      int cch = tid + 256 * it;
      int r = cch >> 2, cc = cch & 3;
      size_t ao = (size_t)(m0 + r) * Kd + k0 + cc * 8;
      size_t bo = (size_t)(n0 + r) * Kd + k0 + cc * 8;
      *(i32x4*)&AshH[r][cc * 8] = *(const i32x4*)(Ah + ao);
      *(i32x4*)&AshL[r][cc * 8] = *(const i32x4*)(Al + ao);
      *(i32x4*)&BshH[r][cc * 8] = *(const i32x4*)(Bzh + bo);
      *(i32x4*)&BshL[r][cc * 8] = *(const i32x4*)(Bzl + bo);
    }
    __syncthreads();
    short8 afh[4], afl[4], bfh[4], bfl[4];
#pragma unroll
    for (int mt = 0; mt < 4; ++mt) {
      afh[mt] = *(const short8*)&AshH[wm + mt * 16 + lr][g * 8];
      afl[mt] = *(const short8*)&AshL[wm + mt * 16 + lr][g * 8];
    }
#pragma unroll
    for (int nt = 0; nt < 4; ++nt) {
      bfh[nt] = *(const short8*)&BshH[wn + nt * 16 + lr][g * 8];
      bfl[nt] = *(const short8*)&BshL[wn + nt * 16 + lr][g * 8];
    }
#pragma unroll
    for (int mt = 0; mt < 4; ++mt)
#pragma unroll
      for (int nt = 0; nt < 4; ++nt) {
        f32x4 a = acc[mt][nt];
        a = __builtin_amdgcn_mfma_f32_16x16x32_bf16(afl[mt], bfh[nt], a, 0, 0, 0);
        a = __builtin_amdgcn_mfma_f32_16x16x32_bf16(afh[mt], bfl[nt], a, 0, 0, 0);
        a = __builtin_amdgcn_mfma_f32_16x16x32_bf16(afh[mt], bfh[nt], a, 0, 0, 0);
        acc[mt][nt] = a;
      }
    __syncthreads();
  }
#pragma unroll
  for (int mt = 0; mt < 4; ++mt)
#pragma unroll
    for (int nt = 0; nt < 4; ++nt)
#pragma unroll
      for (int r = 0; r < 4; ++r) {
        int m = m0 + wm + mt * 16 + g * 4 + r;
        int n = n0 + wn + nt * 16 + lr;
        Cz[(size_t)m * Nd + n] = acc[mt][nt][r];
      }
}

// ---------------- recurrent scan: 1 block (512 thr) per (b,n) chain ----------------
// ROUND-3-VERIFIED skeleton: single Hh/Hl buffer, two barriers per step,
// y computed AFTER the H-write (y_t = q_t . H_{t+1}), RNE hi/lo H writes.
// Deltas from round 3 (each independently verified against round-3 semantics):
//   (1) q/k/v/f staged per 16-step chunk (double-buffered) instead of per-step loads
//   (2) y distributed across all 8 waves (8 hi+lo reads + 3 shfl_xor per lane)
//   (3) 12-MFMA 3-term product (drops Al*Bl ~ 2^-18 rel)
// H layout: row k at byte k*128, elem v at byte (2v) ^ ((k&7)<<4)  [round-3 verified]
__global__ __launch_bounds__(512) void scan_kernel(
    const float* __restrict__ qbuf, const float* __restrict__ kbuf,
    const float* __restrict__ vbuf, const float* __restrict__ fbuf,
    const float* __restrict__ W, unsigned short* __restrict__ yb,
    float* __restrict__ Hout) {
  const int tid = threadIdx.x;
  const int wave = tid >> 6, lane = tid & 63;
  const int g = lane >> 4, lr = lane & 15;
  const int wk = wave & 3, wh = wave >> 2;
  const int b = blockIdx.x >> 3, n = blockIdx.x & 7;
  const int kq = wk * 16 + lr;
  const int swz = (kq & 7) << 4;

  __shared__ unsigned short Hh[64 * 64];   // 8 KB hi plane (round-3 layout)
  __shared__ unsigned short Hl[64 * 64];   // 8 KB lo plane
  __shared__ float stage[2][16][192];      // 24 KB
  __shared__ float fs[2][16];

  for (int i = tid; i < 2048; i += 512) {
    ((unsigned int*)Hh)[i] = 0u;
    ((unsigned int*)Hl)[i] = 0u;
  }

  // W^T split hi/lo fragments (RNE hi) -- round 3 verbatim
  const float* Wn = W + (size_t)n * 4096;
  short8 Af[2][2], Alw[2][2];
#pragma unroll
  for (int u = 0; u < 2; ++u)
#pragma unroll
    for (int s = 0; s < 2; ++s) {
      int wcol = (wh * 2 + u) * 16 + lr;
      short8 ah, al;
#pragma unroll
      for (int j = 0; j < 8; ++j) {
        float wv = Wn[(size_t)(s * 32 + g * 8 + j) * 64 + wcol];
        unsigned short hb = f2bf(wv);
        ah[j] = (short)hb;
        al[j] = (short)f2bf(wv - bf2f(hb));
      }
      Af[u][s] = ah; Alw[u][s] = al;
    }

  // y-phase geometry: column vy, 8 k-rows starting at k0y (full coverage via xor-8/16/32)
  const int vy = wave * 8 + (lane & 7);
  const int k0y = 32 * (lr >> 3) + 8 * g;

  // chunk staging: 16 steps x 192 floats = 768 f32x4
  auto stage_chunk = [&](int c, int buf) {
#pragma unroll
    for (int i = 0; i < 2; ++i) {
      int fi = tid + i * 512;
      if (fi < 768) {
        int st = fi / 48, un = fi - st * 48;
        const float* basep = (un < 16) ? qbuf : (un < 32) ? kbuf : vbuf;
        f32x4 val = *(const f32x4*)(basep + (size_t)(b * 1024 + c * 16 + st) * 512 +
                                    n * 64 + (un & 15) * 4);
        *(f32x4*)&stage[buf][st][un * 4] = val;
      }
    }
    if (tid < 16) fs[buf][tid] = fbuf[(size_t)(b * 1024 + c * 16 + tid) * 8 + n];
  };

  f32x4 HA = (f32x4){0.f, 0.f, 0.f, 0.f};   // f32 master H: H[kq][(2wh+0)*16+4g+r]
  f32x4 HB = (f32x4){0.f, 0.f, 0.f, 0.f};   // H[kq][(2wh+1)*16+4g+r]
  int sb = 0;
  const size_t yrowbase = (size_t)b * 1024 * 512 + n * 64 + vy;

  stage_chunk(0, 0);
  __syncthreads();

  const f32x4 zf = (f32x4){0.f, 0.f, 0.f, 0.f};
  const char* hrh = (const char*)(Hh + kq * 64);
  const char* hrl = (const char*)(Hl + kq * 64);
  char* hwh = (char*)(Hh + kq * 64);
  char* hwl = (char*)(Hl + kq * 64);
  const int bo0 = (16 * g) ^ swz;
  const int bo1 = (64 + 16 * g) ^ swz;
  const int wo0 = ((2 * wh + 0) * 32 + 8 * g) ^ swz;
  const int wo1 = ((2 * wh + 1) * 32 + 8 * g) ^ swz;

  for (int c = 0; c < 64; ++c) {
    if (c < 63) stage_chunk(c + 1, sb ^ 1);
    for (int tl = 0; tl < 16; ++tl) {
      const int tg = c * 16 + tl;
      const float* srow = &stage[sb][tl][0];

      // B-frags of H_t (hi + lo) -- round 3 verbatim
      short8 Bh0 = *(const short8*)(hrh + bo0);
      short8 Bh1 = *(const short8*)(hrh + bo1);
      short8 Bl0 = *(const short8*)(hrl + bo0);
      short8 Bl1 = *(const short8*)(hrl + bo1);

      // 12 MFMAs: 3-term (Ah*Bh + Al*Bh + Ah*Bl), 4 independent chains of 3
      f32x4 cA0 = __builtin_amdgcn_mfma_f32_16x16x32_bf16(Alw[0][0], Bh0, zf, 0, 0, 0);
      f32x4 cB0 = __builtin_amdgcn_mfma_f32_16x16x32_bf16(Alw[0][1], Bh1, zf, 0, 0, 0);
      f32x4 cA1 = __builtin_amdgcn_mfma_f32_16x16x32_bf16(Alw[1][0], Bh0, zf, 0, 0, 0);
      f32x4 cB1 = __builtin_amdgcn_mfma_f32_16x16x32_bf16(Alw[1][1], Bh1, zf, 0, 0, 0);
      cA0 = __builtin_amdgcn_mfma_f32_16x16x32_bf16(Af[0][1], Bh1, cA0, 0, 0, 0);
      cB0 = __builtin_amdgcn_mfma_f32_16x16x32_bf16(Af[0][1], Bl1, cB0, 0, 0, 0);
      cA1 = __builtin_amdgcn_mfma_f32_16x16x32_bf16(Af[1][1], Bh1, cA1, 0, 0, 0);
      cB1 = __builtin_amdgcn_mfma_f32_16x16x32_bf16(Af[1][1], Bl1, cB1, 0, 0, 0);
      cA0 = __builtin_amdgcn_mfma_f32_16x16x32_bf16(Af[0][0], Bh0, cA0, 0, 0, 0);
      cB0 = __builtin_amdgcn_mfma_f32_16x16x32_bf16(Af[0][0], Bl0, cB0, 0, 0, 0);
      cA1 = __builtin_amdgcn_mfma_f32_16x16x32_bf16(Af[1][0], Bh0, cA1, 0, 0, 0);
      cB1 = __builtin_amdgcn_mfma_f32_16x16x32_bf16(Af[1][0], Bl0, cB1, 0, 0, 0);

      float kval = srow[64 + kq];
      f32x4 vv0 = *(const f32x4*)(srow + 128 + (2 * wh + 0) * 16 + 4 * g);
      f32x4 vv1 = *(const f32x4*)(srow + 128 + (2 * wh + 1) * 16 + 4 * g);
      float fc = fs[sb][tl];

      f32x4 a0 = cA0 + cB0;
      f32x4 a1 = cA1 + cB1;

      float gf = fc, omg = 1.f - fc;
#pragma unroll
      for (int r = 0; r < 4; ++r) {
        float c0 = tanhf_fast(a0[r] + kval * vv0[r]);
        HA[r] = gf * HA[r] + omg * c0;
        float c1 = tanhf_fast(a1[r] + kval * vv1[r]);
        HB[r] = gf * HB[r] + omg * c1;
      }

      __syncthreads();  // B1: all H_t reads done

      {  // write H_{t+1} RNE hi+lo -- round 3 verbatim
        unsigned short h0 = f2bf(HA[0]), h1 = f2bf(HA[1]);
        unsigned short h2 = f2bf(HA[2]), h3 = f2bf(HA[3]);
        unsigned short l0 = f2bf(HA[0] - bf2f(h0)), l1 = f2bf(HA[1] - bf2f(h1));
        unsigned short l2 = f2bf(HA[2] - bf2f(h2)), l3 = f2bf(HA[3] - bf2f(h3));
        u32x2 ph = {(unsigned)h0 | ((unsigned)h1 << 16), (unsigned)h2 | ((unsigned)h3 << 16)};
        u32x2 pl = {(unsigned)l0 | ((unsigned)l1 << 16), (unsigned)l2 | ((unsigned)l3 << 16)};
        *(u32x2*)(hwh + wo0) = ph;
        *(u32x2*)(hwl + wo0) = pl;
        h0 = f2bf(HB[0]); h1 = f2bf(HB[1]); h2 = f2bf(HB[2]); h3 = f2bf(HB[3]);
        l0 = f2bf(HB[0] - bf2f(h0)); l1 = f2bf(HB[1] - bf2f(h1));
        l2 = f2bf(HB[2] - bf2f(h2)); l3 = f2bf(HB[3] - bf2f(h3));
        ph = (u32x2){(unsigned)h0 | ((unsigned)h1 << 16), (unsigned)h2 | ((unsigned)h3 << 16)};
        pl = (u32x2){(unsigned)l0 | ((unsigned)l1 << 16), (unsigned)l2 | ((unsigned)l3 << 16)};
        *(u32x2*)(hwh + wo1) = ph;
        *(u32x2*)(hwl + wo1) = pl;
      }

      __syncthreads();  // B2: Hh/Hl = H_{t+1}

      // y_t = q_t . H_{t+1}, distributed across all 8 waves
      {
        float ys = 0.f;
#pragma unroll
        for (int j = 0; j < 8; ++j) {
          int boff = (k0y + j) * 128 + ((2 * vy) ^ (j << 4));
          float hv = bf2f(*(const unsigned short*)((const char*)Hh + boff)) +
                     bf2f(*(const unsigned short*)((const char*)Hl + boff));
          ys += srow[k0y + j] * hv;
        }
        ys += __shfl_xor(ys, 8, 64);
        ys += __shfl_xor(ys, 16, 64);
        ys += __shfl_xor(ys, 32, 64);
        if (lane < 8) yb[yrowbase + (size_t)tg * 512] = f2bf(ys);
      }
    }
    sb ^= 1;
  }

  // H_final (f32 master)
  float* Ho = Hout + (size_t)(b * 8 + n) * 4096;
  *(f32x4*)&Ho[(size_t)kq * 64 + (wh * 2 + 0) * 16 + g * 4] = HA;
  *(f32x4*)&Ho[(size_t)kq * 64 + (wh * 2 + 1) * 16 + g * 4] = HB;
}

// ---------------- launch ----------------
extern "C" void kernel_launch(void* const* d_in, const int* in_sizes, int n_in,
                              void* d_out, int out_size, void* d_ws, size_t ws_size,
                              hipStream_t stream) {
  const float* x   = (const float*)d_in[0];
  const float* Wq  = (const float*)d_in[1];
  const float* Wk  = (const float*)d_in[2];
  const float* Wv  = (const float*)d_in[3];
  const float* Wf  = (const float*)d_in[4];
  const float* bfv = (const float*)d_in[5];
  const float* cwq = (const float*)d_in[6];
  const float* cwk = (const float*)d_in[7];
  const float* cwv = (const float*)d_in[8];
  const float* W   = (const float*)d_in[9];
  const float* Wo  = (const float*)d_in[10];
  float* outp = (float*)d_out;

  char* ws = (char*)d_ws;
  size_t off = 0;
  auto alloc = [&](size_t bytes) {
    char* pp = ws + off;
    off = (off + bytes + 255) & ~(size_t)255;
    return pp;
  };
  unsigned short* xbh  = (unsigned short*)alloc((size_t)4194304 * 2);
  unsigned short* xbl  = (unsigned short*)alloc((size_t)4194304 * 2);
  unsigned short* wtbh = (unsigned short*)alloc((size_t)3 * 524288 * 2);
  unsigned short* wtbl = (unsigned short*)alloc((size_t)3 * 524288 * 2);
  float* pre  = (float*)alloc((size_t)3 * 2097152 * 4);
  float* qkv  = (float*)alloc((size_t)3 * 2097152 * 4);
  float* fbuf = (float*)alloc((size_t)32768 * 4);
  unsigned short* yb  = (unsigned short*)alloc((size_t)2097152 * 2);
  unsigned short* wot = (unsigned short*)alloc((size_t)524288 * 2);

  // casts / transposes (split hi/lo for the amplified paths)
  cast_split_kernel<<<4096, 256, 0, stream>>>(x, xbh, xbl, 1048576);
  tcast_split_kernel<<<2048, 256, 0, stream>>>(Wq, wtbh, wtbl, 1024, 512);
  tcast_split_kernel<<<2048, 256, 0, stream>>>(Wk, wtbh + 524288, wtbl + 524288, 1024, 512);
  tcast_split_kernel<<<2048, 256, 0, stream>>>(Wv, wtbh + 2 * 524288, wtbl + 2 * 524288, 1024, 512);
  // gate
  fgate_kernel<<<1024, 256, 0, stream>>>(x, Wf, bfv, fbuf);
  // q pre-activation: plain bf16 (un-amplified path)
  dim3 gq(32, 4, 1);
  gemm_bf16_kernel<<<gq, 256, 0, stream>>>(xbh, wtbh, pre, 1024, 512,
                                           (size_t)0, (size_t)0);
  // k,v pre-activations: split-bf16 (amplified path)
  dim3 gkv(32, 4, 2);
  gemm_split_kernel<<<gkv, 256, 0, stream>>>(xbh, xbl, wtbh + 524288, wtbl + 524288,
                                             pre + 2097152, 1024, 512,
                                             (size_t)524288, (size_t)2097152);
  // conv + silu (all three in one launch)
  dim3 gc(8192, 3, 1);
  conv_silu_kernel<<<gc, 256, 0, stream>>>(pre, cwq, cwk, cwv, qkv);
  // recurrent scan (writes yb bf16 and H_final tail of d_out)
  scan_kernel<<<32, 512, 0, stream>>>(qkv, qkv + 2097152, qkv + 2 * 2097152, fbuf, W,
                                      yb, outp + 4194304);
  // output projection
  tcast_kernel<<<2048, 256, 0, stream>>>(Wo, wot, 512, 1024);
  dim3 g2(32, 8, 1);
  gemm_bf16_kernel<<<g2, 256, 0, stream>>>(yb, wot, outp, 512, 1024, (size_t)0, (size_t)0);
}

// Round 7
// 1685.084 us; speedup vs baseline: 1.0666x; 1.0666x over previous
//
#include <hip/hip_runtime.h>
#include <hip/hip_bf16.h>

typedef __attribute__((ext_vector_type(4))) float f32x4;
typedef __attribute__((ext_vector_type(8))) short short8;
typedef __attribute__((ext_vector_type(4))) int i32x4;
typedef __attribute__((ext_vector_type(2))) unsigned int u32x2;
typedef __attribute__((ext_vector_type(4))) unsigned int u32x4;
typedef __attribute__((ext_vector_type(4))) unsigned short u16x4;

static __device__ __forceinline__ unsigned short f2bf(float f) {
  unsigned u = __builtin_bit_cast(unsigned, f);
  u = u + 0x7FFFu + ((u >> 16) & 1u);   // RNE
  return (unsigned short)(u >> 16);
}
static __device__ __forceinline__ float bf2f(unsigned short b) {
  unsigned u = ((unsigned)b) << 16;
  return __builtin_bit_cast(float, u);
}
static __device__ __forceinline__ float sigmoidf_fast(float x) {
  return __builtin_amdgcn_rcpf(1.f + __expf(-x));
}
static __device__ __forceinline__ float tanhf_fast(float x) {
  x = fminf(20.f, fmaxf(-20.f, x));
  float e = __expf(2.f * x);
  return (e - 1.f) * __builtin_amdgcn_rcpf(e + 1.f);
}

// ---------------- cast f32 -> hi/lo bf16 pair (RNE hi) ----------------
__global__ void cast_split_kernel(const float* __restrict__ in,
                                  unsigned short* __restrict__ oh,
                                  unsigned short* __restrict__ ol, int n4) {
  int i = blockIdx.x * blockDim.x + threadIdx.x;
  if (i >= n4) return;
  f32x4 v = ((const f32x4*)in)[i];
  u16x4 h, l;
#pragma unroll
  for (int j = 0; j < 4; ++j) {
    unsigned short hb = f2bf(v[j]);
    h[j] = hb;
    l[j] = f2bf(v[j] - bf2f(hb));
  }
  ((u16x4*)oh)[i] = h;
  ((u16x4*)ol)[i] = l;
}

// ---------------- transpose + cast: (R,C) f32 -> (C,R) bf16 ----------------
__global__ void tcast_kernel(const float* __restrict__ in,
                             unsigned short* __restrict__ out, int R, int C) {
  int i = blockIdx.x * blockDim.x + threadIdx.x;
  if (i >= R * C) return;
  int r = i / C, c = i % C;
  out[(size_t)c * R + r] = f2bf(in[i]);
}

// ---------------- transpose + split cast: (R,C) f32 -> (C,R) hi/lo bf16 ----------------
__global__ void tcast_split_kernel(const float* __restrict__ in,
                                   unsigned short* __restrict__ oh,
                                   unsigned short* __restrict__ ol, int R, int C) {
  int i = blockIdx.x * blockDim.x + threadIdx.x;
  if (i >= R * C) return;
  int r = i / C, c = i % C;
  float v = in[i];
  unsigned short hb = f2bf(v);
  oh[(size_t)c * R + r] = hb;
  ol[(size_t)c * R + r] = f2bf(v - bf2f(hb));
}

// ---------------- f gate: one wave per token row (pure f32) ----------------
__global__ __launch_bounds__(256) void fgate_kernel(const float* __restrict__ x,
                                                    const float* __restrict__ Wf,
                                                    const float* __restrict__ bfv,
                                                    float* __restrict__ fbuf) {
  int wid = (blockIdx.x * blockDim.x + threadIdx.x) >> 6;  // token row 0..4095
  int lane = threadIdx.x & 63;
  const float* xr = x + (size_t)wid * 1024;
  float acc[8] = {0.f, 0.f, 0.f, 0.f, 0.f, 0.f, 0.f, 0.f};
#pragma unroll 4
  for (int it = 0; it < 16; ++it) {
    int d = it * 64 + lane;
    float xv = xr[d];
    f32x4 w0 = *(const f32x4*)(Wf + (size_t)d * 8);
    f32x4 w1 = *(const f32x4*)(Wf + (size_t)d * 8 + 4);
    acc[0] += xv * w0[0]; acc[1] += xv * w0[1];
    acc[2] += xv * w0[2]; acc[3] += xv * w0[3];
    acc[4] += xv * w1[0]; acc[5] += xv * w1[1];
    acc[6] += xv * w1[2]; acc[7] += xv * w1[3];
  }
#pragma unroll
  for (int n = 0; n < 8; ++n) {
#pragma unroll
    for (int m = 1; m < 64; m <<= 1) acc[n] += __shfl_xor(acc[n], m, 64);
  }
  if (lane == 0) {
#pragma unroll
    for (int n = 0; n < 8; ++n)
      fbuf[(size_t)wid * 8 + n] = sigmoidf_fast(acc[n] + bfv[n]);
  }
}

// ---------------- causal depthwise conv (KC=4) + SiLU, all 3 tensors ----------------
__global__ void conv_silu_kernel(const float* __restrict__ pre,
                                 const float* __restrict__ cwq,
                                 const float* __restrict__ cwk,
                                 const float* __restrict__ cwv,
                                 float* __restrict__ outb) {
  int i = blockIdx.x * blockDim.x + threadIdx.x;  // B*L*512
  int which = blockIdx.y;
  const float* cw = (which == 0) ? cwq : (which == 1) ? cwk : cwv;
  const float* p = pre + (size_t)which * 2097152 + i;
  int c = i & 511;
  int l = (i >> 9) & 1023;
  float w0 = cw[c * 4 + 0], w1 = cw[c * 4 + 1], w2 = cw[c * 4 + 2], w3 = cw[c * 4 + 3];
  float acc = w3 * p[0];
  if (l >= 1) acc += w2 * p[-512];
  if (l >= 2) acc += w1 * p[-1024];
  if (l >= 3) acc += w0 * p[-1536];
  outb[(size_t)which * 2097152 + i] = acc * sigmoidf_fast(acc);
}

// ---------------- plain bf16 MFMA GEMM: C(M,Nd) = A * Bt^T ----------------
__global__ __launch_bounds__(256) void gemm_bf16_kernel(
    const unsigned short* __restrict__ A, const unsigned short* __restrict__ Bt,
    float* __restrict__ C, int Kd, int Nd, size_t BtStride, size_t CStride) {
  __shared__ unsigned short Ash[128][40];
  __shared__ unsigned short Bsh[128][40];
  const int tid = threadIdx.x;
  const int wave = tid >> 6, lane = tid & 63;
  const int g = lane >> 4, lr = lane & 15;
  const int m0 = blockIdx.x * 128, n0 = blockIdx.y * 128;
  const unsigned short* Bz = Bt + blockIdx.z * BtStride;
  float* Cz = C + blockIdx.z * CStride;
  const int wm = (wave >> 1) * 64, wn = (wave & 1) * 64;

  f32x4 acc[4][4];
#pragma unroll
  for (int a = 0; a < 4; ++a)
#pragma unroll
    for (int bq = 0; bq < 4; ++bq) acc[a][bq] = (f32x4){0.f, 0.f, 0.f, 0.f};

  for (int k0 = 0; k0 < Kd; k0 += 32) {
#pragma unroll
    for (int it = 0; it < 2; ++it) {
      int cch = tid + 256 * it;
      int r = cch >> 2, cc = cch & 3;
      *(i32x4*)&Ash[r][cc * 8] = *(const i32x4*)(A + (size_t)(m0 + r) * Kd + k0 + cc * 8);
      *(i32x4*)&Bsh[r][cc * 8] = *(const i32x4*)(Bz + (size_t)(n0 + r) * Kd + k0 + cc * 8);
    }
    __syncthreads();
    short8 af[4], bfr[4];
#pragma unroll
    for (int mt = 0; mt < 4; ++mt) af[mt] = *(const short8*)&Ash[wm + mt * 16 + lr][g * 8];
#pragma unroll
    for (int nt = 0; nt < 4; ++nt) bfr[nt] = *(const short8*)&Bsh[wn + nt * 16 + lr][g * 8];
#pragma unroll
    for (int mt = 0; mt < 4; ++mt)
#pragma unroll
      for (int nt = 0; nt < 4; ++nt)
        acc[mt][nt] = __builtin_amdgcn_mfma_f32_16x16x32_bf16(af[mt], bfr[nt], acc[mt][nt], 0, 0, 0);
    __syncthreads();
  }
#pragma unroll
  for (int mt = 0; mt < 4; ++mt)
#pragma unroll
    for (int nt = 0; nt < 4; ++nt)
#pragma unroll
      for (int r = 0; r < 4; ++r) {
        int m = m0 + wm + mt * 16 + g * 4 + r;
        int n = n0 + wn + nt * 16 + lr;
        Cz[(size_t)m * Nd + n] = acc[mt][nt][r];
      }
}

// ---------------- split-bf16 (3-term f32-emulation) GEMM ----------------
__global__ __launch_bounds__(256) void gemm_split_kernel(
    const unsigned short* __restrict__ Ah, const unsigned short* __restrict__ Al,
    const unsigned short* __restrict__ Bth, const unsigned short* __restrict__ Btl,
    float* __restrict__ C, int Kd, int Nd, size_t BtStride, size_t CStride) {
  __shared__ unsigned short AshH[128][40];
  __shared__ unsigned short AshL[128][40];
  __shared__ unsigned short BshH[128][40];
  __shared__ unsigned short BshL[128][40];
  const int tid = threadIdx.x;
  const int wave = tid >> 6, lane = tid & 63;
  const int g = lane >> 4, lr = lane & 15;
  const int m0 = blockIdx.x * 128, n0 = blockIdx.y * 128;
  const unsigned short* Bzh = Bth + blockIdx.z * BtStride;
  const unsigned short* Bzl = Btl + blockIdx.z * BtStride;
  float* Cz = C + blockIdx.z * CStride;
  const int wm = (wave >> 1) * 64, wn = (wave & 1) * 64;

  f32x4 acc[4][4];
#pragma unroll
  for (int a = 0; a < 4; ++a)
#pragma unroll
    for (int bq = 0; bq < 4; ++bq) acc[a][bq] = (f32x4){0.f, 0.f, 0.f, 0.f};

  for (int k0 = 0; k0 < Kd; k0 += 32) {
#pragma unroll
    for (int it = 0; it < 2; ++it) {
      int cch = tid + 256 * it;
      int r = cch >> 2, cc = cch & 3;
      size_t ao = (size_t)(m0 + r) * Kd + k0 + cc * 8;
      size_t bo = (size_t)(n0 + r) * Kd + k0 + cc * 8;
      *(i32x4*)&AshH[r][cc * 8] = *(const i32x4*)(Ah + ao);
      *(i32x4*)&AshL[r][cc * 8] = *(const i32x4*)(Al + ao);
      *(i32x4*)&BshH[r][cc * 8] = *(const i32x4*)(Bzh + bo);
      *(i32x4*)&BshL[r][cc * 8] = *(const i32x4*)(Bzl + bo);
    }
    __syncthreads();
    short8 afh[4], afl[4], bfh[4], bfl[4];
#pragma unroll
    for (int mt = 0; mt < 4; ++mt) {
      afh[mt] = *(const short8*)&AshH[wm + mt * 16 + lr][g * 8];
      afl[mt] = *(const short8*)&AshL[wm + mt * 16 + lr][g * 8];
    }
#pragma unroll
    for (int nt = 0; nt < 4; ++nt) {
      bfh[nt] = *(const short8*)&BshH[wn + nt * 16 + lr][g * 8];
      bfl[nt] = *(const short8*)&BshL[wn + nt * 16 + lr][g * 8];
    }
#pragma unroll
    for (int mt = 0; mt < 4; ++mt)
#pragma unroll
      for (int nt = 0; nt < 4; ++nt) {
        f32x4 a = acc[mt][nt];
        a = __builtin_amdgcn_mfma_f32_16x16x32_bf16(afl[mt], bfh[nt], a, 0, 0, 0);
        a = __builtin_amdgcn_mfma_f32_16x16x32_bf16(afh[mt], bfl[nt], a, 0, 0, 0);
        a = __builtin_amdgcn_mfma_f32_16x16x32_bf16(afh[mt], bfh[nt], a, 0, 0, 0);
        acc[mt][nt] = a;
      }
    __syncthreads();
  }
#pragma unroll
  for (int mt = 0; mt < 4; ++mt)
#pragma unroll
    for (int nt = 0; nt < 4; ++nt)
#pragma unroll
      for (int r = 0; r < 4; ++r) {
        int m = m0 + wm + mt * 16 + g * 4 + r;
        int n = n0 + wn + nt * 16 + lr;
        Cz[(size_t)m * Nd + n] = acc[mt][nt][r];
      }
}

// ---------------- recurrent scan: 1 block (512 thr) per (b,n) chain ----------------
// Round-6-verified skeleton (single Hh/Hl buffer, 2 barriers/step, y after write).
// Round-7 deltas:
//   (1) Ht[k][w] packed u32 copy (hi<<16|lo) written as 2x ds_write_b128/lane;
//       y reads 8 single-u32 (2-way conflict = free) instead of 16 8-way u16 reads.
//   (2) y buffered in LDS (yst), flushed to global once per 16-step chunk.
//   (3) y's q read as 2x b128.
// Row-major planes: row k at byte k*128, elem v at byte (2v) ^ ((k&7)<<4).
// Ht: row k at byte k*256, col w at byte (4w) ^ ((k&7)<<5)  (same XOR both sides).
__global__ __launch_bounds__(512) void scan_kernel(
    const float* __restrict__ qbuf, const float* __restrict__ kbuf,
    const float* __restrict__ vbuf, const float* __restrict__ fbuf,
    const float* __restrict__ W, unsigned short* __restrict__ yb,
    float* __restrict__ Hout) {
  const int tid = threadIdx.x;
  const int wave = tid >> 6, lane = tid & 63;
  const int g = lane >> 4, lr = lane & 15;
  const int wk = wave & 3, wh = wave >> 2;
  const int b = blockIdx.x >> 3, n = blockIdx.x & 7;
  const int kq = wk * 16 + lr;
  const int swz = (kq & 7) << 4;

  __shared__ unsigned short Hh[64 * 64];   // 8 KB hi plane (row-major, swizzled)
  __shared__ unsigned short Hl[64 * 64];   // 8 KB lo plane
  __shared__ unsigned Ht[64 * 64];         // 16 KB transposed packed copy [k][w]
  __shared__ float stage[2][16][192];      // 24 KB
  __shared__ float fs[2][16];
  __shared__ unsigned short yst[16 * 64];  // 2 KB y chunk buffer

  for (int i = tid; i < 2048; i += 512) {
    ((unsigned int*)Hh)[i] = 0u;
    ((unsigned int*)Hl)[i] = 0u;
  }

  // W^T split hi/lo fragments (RNE hi) -- round 6 verbatim
  const float* Wn = W + (size_t)n * 4096;
  short8 Af[2][2], Alw[2][2];
#pragma unroll
  for (int u = 0; u < 2; ++u)
#pragma unroll
    for (int s = 0; s < 2; ++s) {
      int wcol = (wh * 2 + u) * 16 + lr;
      short8 ah, al;
#pragma unroll
      for (int j = 0; j < 8; ++j) {
        float wv = Wn[(size_t)(s * 32 + g * 8 + j) * 64 + wcol];
        unsigned short hb = f2bf(wv);
        ah[j] = (short)hb;
        al[j] = (short)f2bf(wv - bf2f(hb));
      }
      Af[u][s] = ah; Alw[u][s] = al;
    }

  // y-phase geometry (round 6): column vy, 8 k-rows at k0y; xor-8/16/32 covers k
  const int vy = wave * 8 + (lane & 7);
  const int k0y = 32 * (lr >> 3) + 8 * g;

  // Ht addresses
  char* Htb = (char*)Ht;
  char* htwA = Htb + kq * 256 + ((64 * (2 * wh + 0) + 16 * g) ^ ((kq & 7) << 5));
  char* htwB = Htb + kq * 256 + ((64 * (2 * wh + 1) + 16 * g) ^ ((kq & 7) << 5));
  const char* htR[8];
#pragma unroll
  for (int j = 0; j < 8; ++j)
    htR[j] = Htb + (k0y + j) * 256 + ((4 * vy) ^ (j << 5));

  // chunk staging: 16 steps x 192 floats = 768 f32x4
  auto stage_chunk = [&](int c, int buf) {
#pragma unroll
    for (int i = 0; i < 2; ++i) {
      int fi = tid + i * 512;
      if (fi < 768) {
        int st = fi / 48, un = fi - st * 48;
        const float* basep = (un < 16) ? qbuf : (un < 32) ? kbuf : vbuf;
        f32x4 val = *(const f32x4*)(basep + (size_t)(b * 1024 + c * 16 + st) * 512 +
                                    n * 64 + (un & 15) * 4);
        *(f32x4*)&stage[buf][st][un * 4] = val;
      }
    }
    if (tid < 16) fs[buf][tid] = fbuf[(size_t)(b * 1024 + c * 16 + tid) * 8 + n];
  };

  f32x4 HA = (f32x4){0.f, 0.f, 0.f, 0.f};   // f32 master H: H[kq][(2wh+0)*16+4g+r]
  f32x4 HB = (f32x4){0.f, 0.f, 0.f, 0.f};   // H[kq][(2wh+1)*16+4g+r]
  int sb = 0;

  stage_chunk(0, 0);
  __syncthreads();

  const f32x4 zf = (f32x4){0.f, 0.f, 0.f, 0.f};
  const char* hrh = (const char*)(Hh + kq * 64);
  const char* hrl = (const char*)(Hl + kq * 64);
  char* hwh = (char*)(Hh + kq * 64);
  char* hwl = (char*)(Hl + kq * 64);
  const int bo0 = (16 * g) ^ swz;
  const int bo1 = (64 + 16 * g) ^ swz;
  const int wo0 = ((2 * wh + 0) * 32 + 8 * g) ^ swz;
  const int wo1 = ((2 * wh + 1) * 32 + 8 * g) ^ swz;

  for (int c = 0; c < 64; ++c) {
    if (c < 63) stage_chunk(c + 1, sb ^ 1);
    for (int tl = 0; tl < 16; ++tl) {
      const float* srow = &stage[sb][tl][0];

      // B-frags of H_t (hi + lo) -- round 6 verbatim
      short8 Bh0 = *(const short8*)(hrh + bo0);
      short8 Bh1 = *(const short8*)(hrh + bo1);
      short8 Bl0 = *(const short8*)(hrl + bo0);
      short8 Bl1 = *(const short8*)(hrl + bo1);

      // 12 MFMAs: 3-term, 4 independent chains of 3 -- round 6 verbatim
      f32x4 cA0 = __builtin_amdgcn_mfma_f32_16x16x32_bf16(Alw[0][0], Bh0, zf, 0, 0, 0);
      f32x4 cB0 = __builtin_amdgcn_mfma_f32_16x16x32_bf16(Alw[0][1], Bh1, zf, 0, 0, 0);
      f32x4 cA1 = __builtin_amdgcn_mfma_f32_16x16x32_bf16(Alw[1][0], Bh0, zf, 0, 0, 0);
      f32x4 cB1 = __builtin_amdgcn_mfma_f32_16x16x32_bf16(Alw[1][1], Bh1, zf, 0, 0, 0);
      cA0 = __builtin_amdgcn_mfma_f32_16x16x32_bf16(Af[0][1], Bh1, cA0, 0, 0, 0);
      cB0 = __builtin_amdgcn_mfma_f32_16x16x32_bf16(Af[0][1], Bl1, cB0, 0, 0, 0);
      cA1 = __builtin_amdgcn_mfma_f32_16x16x32_bf16(Af[1][1], Bh1, cA1, 0, 0, 0);
      cB1 = __builtin_amdgcn_mfma_f32_16x16x32_bf16(Af[1][1], Bl1, cB1, 0, 0, 0);
      cA0 = __builtin_amdgcn_mfma_f32_16x16x32_bf16(Af[0][0], Bh0, cA0, 0, 0, 0);
      cB0 = __builtin_amdgcn_mfma_f32_16x16x32_bf16(Af[0][0], Bl0, cB0, 0, 0, 0);
      cA1 = __builtin_amdgcn_mfma_f32_16x16x32_bf16(Af[1][0], Bh0, cA1, 0, 0, 0);
      cB1 = __builtin_amdgcn_mfma_f32_16x16x32_bf16(Af[1][0], Bl0, cB1, 0, 0, 0);

      float kval = srow[64 + kq];
      f32x4 vv0 = *(const f32x4*)(srow + 128 + (2 * wh + 0) * 16 + 4 * g);
      f32x4 vv1 = *(const f32x4*)(srow + 128 + (2 * wh + 1) * 16 + 4 * g);
      float fc = fs[sb][tl];

      f32x4 a0 = cA0 + cB0;
      f32x4 a1 = cA1 + cB1;

      float gf = fc, omg = 1.f - fc;
#pragma unroll
      for (int r = 0; r < 4; ++r) {
        float c0 = tanhf_fast(a0[r] + kval * vv0[r]);
        HA[r] = gf * HA[r] + omg * c0;
        float c1 = tanhf_fast(a1[r] + kval * vv1[r]);
        HB[r] = gf * HB[r] + omg * c1;
      }

      __syncthreads();  // B1: all H_t reads done

      {  // write H_{t+1}: row-major hi+lo (round 6 verbatim) + packed Ht copy
        unsigned short h0 = f2bf(HA[0]), h1 = f2bf(HA[1]);
        unsigned short h2 = f2bf(HA[2]), h3 = f2bf(HA[3]);
        unsigned short l0 = f2bf(HA[0] - bf2f(h0)), l1 = f2bf(HA[1] - bf2f(h1));
        unsigned short l2 = f2bf(HA[2] - bf2f(h2)), l3 = f2bf(HA[3] - bf2f(h3));
        u32x2 ph = {(unsigned)h0 | ((unsigned)h1 << 16), (unsigned)h2 | ((unsigned)h3 << 16)};
        u32x2 pl = {(unsigned)l0 | ((unsigned)l1 << 16), (unsigned)l2 | ((unsigned)l3 << 16)};
        *(u32x2*)(hwh + wo0) = ph;
        *(u32x2*)(hwl + wo0) = pl;
        u32x4 hta = {((unsigned)h0 << 16) | l0, ((unsigned)h1 << 16) | l1,
                     ((unsigned)h2 << 16) | l2, ((unsigned)h3 << 16) | l3};
        *(u32x4*)htwA = hta;

        h0 = f2bf(HB[0]); h1 = f2bf(HB[1]); h2 = f2bf(HB[2]); h3 = f2bf(HB[3]);
        l0 = f2bf(HB[0] - bf2f(h0)); l1 = f2bf(HB[1] - bf2f(h1));
        l2 = f2bf(HB[2] - bf2f(h2)); l3 = f2bf(HB[3] - bf2f(h3));
        ph = (u32x2){(unsigned)h0 | ((unsigned)h1 << 16), (unsigned)h2 | ((unsigned)h3 << 16)};
        pl = (u32x2){(unsigned)l0 | ((unsigned)l1 << 16), (unsigned)l2 | ((unsigned)l3 << 16)};
        *(u32x2*)(hwh + wo1) = ph;
        *(u32x2*)(hwl + wo1) = pl;
        u32x4 htb = {((unsigned)h0 << 16) | l0, ((unsigned)h1 << 16) | l1,
                     ((unsigned)h2 << 16) | l2, ((unsigned)h3 << 16) | l3};
        *(u32x4*)htwB = htb;
      }

      __syncthreads();  // B2: Hh/Hl/Ht = H_{t+1}

      // y_t = q_t . H_{t+1} from the packed Ht copy
      {
        f32x4 qy0 = *(const f32x4*)(srow + k0y);
        f32x4 qy1 = *(const f32x4*)(srow + k0y + 4);
        float ys = 0.f;
#pragma unroll
        for (int j = 0; j < 8; ++j) {
          unsigned uu = *(const unsigned*)htR[j];
          float hv = __builtin_bit_cast(float, uu & 0xFFFF0000u) +
                     __builtin_bit_cast(float, uu << 16);
          float qv = (j < 4) ? qy0[j] : qy1[j - 4];
          ys += qv * hv;
        }
        ys += __shfl_xor(ys, 8, 64);
        ys += __shfl_xor(ys, 16, 64);
        ys += __shfl_xor(ys, 32, 64);
        if (lane < 8) yst[tl * 64 + vy] = f2bf(ys);
      }
    }

    __syncthreads();  // yst complete for this chunk
    {  // flush y chunk: 512 threads x one u32 (2 bf16) coalesced
      int tl2 = tid >> 5, pv = (tid & 31) << 1;
      unsigned val = ((const unsigned*)yst)[tid];
      *(unsigned*)(yb + (size_t)(b * 1024 + c * 16 + tl2) * 512 + n * 64 + pv) = val;
    }
    sb ^= 1;
  }

  // H_final (f32 master)
  float* Ho = Hout + (size_t)(b * 8 + n) * 4096;
  *(f32x4*)&Ho[(size_t)kq * 64 + (wh * 2 + 0) * 16 + g * 4] = HA;
  *(f32x4*)&Ho[(size_t)kq * 64 + (wh * 2 + 1) * 16 + g * 4] = HB;
}

// ---------------- launch ----------------
extern "C" void kernel_launch(void* const* d_in, const int* in_sizes, int n_in,
                              void* d_out, int out_size, void* d_ws, size_t ws_size,
                              hipStream_t stream) {
  const float* x   = (const float*)d_in[0];
  const float* Wq  = (const float*)d_in[1];
  const float* Wk  = (const float*)d_in[2];
  const float* Wv  = (const float*)d_in[3];
  const float* Wf  = (const float*)d_in[4];
  const float* bfv = (const float*)d_in[5];
  const float* cwq = (const float*)d_in[6];
  const float* cwk = (const float*)d_in[7];
  const float* cwv = (const float*)d_in[8];
  const float* W   = (const float*)d_in[9];
  const float* Wo  = (const float*)d_in[10];
  float* outp = (float*)d_out;

  char* ws = (char*)d_ws;
  size_t off = 0;
  auto alloc = [&](size_t bytes) {
    char* pp = ws + off;
    off = (off + bytes + 255) & ~(size_t)255;
    return pp;
  };
  unsigned short* xbh  = (unsigned short*)alloc((size_t)4194304 * 2);
  unsigned short* xbl  = (unsigned short*)alloc((size_t)4194304 * 2);
  unsigned short* wtbh = (unsigned short*)alloc((size_t)3 * 524288 * 2);
  unsigned short* wtbl = (unsigned short*)alloc((size_t)3 * 524288 * 2);
  float* pre  = (float*)alloc((size_t)3 * 2097152 * 4);
  float* qkv  = (float*)alloc((size_t)3 * 2097152 * 4);
  float* fbuf = (float*)alloc((size_t)32768 * 4);
  unsigned short* yb  = (unsigned short*)alloc((size_t)2097152 * 2);
  unsigned short* wot = (unsigned short*)alloc((size_t)524288 * 2);

  // casts / transposes (split hi/lo for the amplified paths)
  cast_split_kernel<<<4096, 256, 0, stream>>>(x, xbh, xbl, 1048576);
  tcast_split_kernel<<<2048, 256, 0, stream>>>(Wq, wtbh, wtbl, 1024, 512);
  tcast_split_kernel<<<2048, 256, 0, stream>>>(Wk, wtbh + 524288, wtbl + 524288, 1024, 512);
  tcast_split_kernel<<<2048, 256, 0, stream>>>(Wv, wtbh + 2 * 524288, wtbl + 2 * 524288, 1024, 512);
  // gate
  fgate_kernel<<<1024, 256, 0, stream>>>(x, Wf, bfv, fbuf);
  // q pre-activation: plain bf16 (un-amplified path)
  dim3 gq(32, 4, 1);
  gemm_bf16_kernel<<<gq, 256, 0, stream>>>(xbh, wtbh, pre, 1024, 512,
                                           (size_t)0, (size_t)0);
  // k,v pre-activations: split-bf16 (amplified path)
  dim3 gkv(32, 4, 2);
  gemm_split_kernel<<<gkv, 256, 0, stream>>>(xbh, xbl, wtbh + 524288, wtbl + 524288,
                                             pre + 2097152, 1024, 512,
                                             (size_t)524288, (size_t)2097152);
  // conv + silu (all three in one launch)
  dim3 gc(8192, 3, 1);
  conv_silu_kernel<<<gc, 256, 0, stream>>>(pre, cwq, cwk, cwv, qkv);
  // recurrent scan (writes yb bf16 and H_final tail of d_out)
  scan_kernel<<<32, 512, 0, stream>>>(qkv, qkv + 2097152, qkv + 2 * 2097152, fbuf, W,
                                      yb, outp + 4194304);
  // output projection
  tcast_kernel<<<2048, 256, 0, stream>>>(Wo, wot, 512, 1024);
  dim3 g2(32, 8, 1);
  gemm_bf16_kernel<<<g2, 256, 0, stream>>>(yb, wot, outp, 512, 1024, (size_t)0, (size_t)0);
}